// Round 18
// baseline (238.699 us; speedup 1.0000x reference)
//
#include <hip/hip_runtime.h>

// NonLocalBlock (SAGAN non-local) fused pipeline for MI355X / gfx950.
// B=8, Cin=256, H=W=64 (HW=4096), Cout=512. Workspace (~46 MB of d_ws):
//   [0,16MB)   xT    fp16 [8][4096][256]
//   [16,20MB)  Q     fp16 [8][4096][64]
//   [20,21MB)  Kp    fp16 [8][1024][64]
//   [21,25MB)  V     fp16 [8][256][1024]
//   [25MB+0)   Wproj fp16 [384][256]
//   [25MB+512K) WcatP fp16 [512][512] fragment-permuted
//
// R17->R18: fix the epilogue spill (R17: WRITE 79.5MB vs 67 expected,
// FETCH 40 vs 27 -> ~25MB scratch round-trip; VGPR squeezed to 64).
// Epilogue now runs in TWO mf-halves (#pragma unroll 1): acc2[2][4]=32
// VGPR per half, peak live ~90 < 128 cap -> no spill. bf LDS reads are
// issued twice (+~800cy/wave, negligible). Everything else identical.

typedef _Float16 f16;
typedef f16 f16x2 __attribute__((ext_vector_type(2)));
typedef f16 f16x4 __attribute__((ext_vector_type(4)));
typedef f16 f16x8 __attribute__((ext_vector_type(8)));
typedef float f32x4 __attribute__((ext_vector_type(4)));

#define MFMA16(a, b, c) __builtin_amdgcn_mfma_f32_16x16x32_f16((a), (b), (c), 0, 0, 0)

__device__ __forceinline__ void gload16(const void* src, void* dst_lds) {
  __builtin_amdgcn_global_load_lds(
      (const __attribute__((address_space(1))) void*)src,
      (__attribute__((address_space(3))) void*)dst_lds, 16, 0, 0);
}

// -------------------------------------------------------------------------
// Weight prep. Wproj as before. WcatP fragment-permuted:
//   Wcat[r][c] -> WcatP[(((r>>4)*16 + (c>>5))*64 + ((c>>3)&3)*16 + (r&15))*8 + (c&7)]
__global__ __launch_bounds__(256, 4)
void k_prep_w(const float* __restrict__ wt, const float* __restrict__ wp,
              const float* __restrict__ wg, const float* __restrict__ wo,
              const float* __restrict__ wr, const float* __restrict__ gamma,
              f16* __restrict__ Wproj, f16* __restrict__ WcatP) {
  int i = blockIdx.x * 256 + threadIdx.x;
  const float s = 0.08838834764831845f;    // sqrt(2/256)
  const float is2 = 0.7071067811865476f;   // 1/sqrt(2)
  if (i < 384 * 256) {
    float v = (i < 64 * 256) ? wt[i]
              : (i < 128 * 256 ? wp[i - 64 * 256] : wg[i - 128 * 256]);
    Wproj[i] = (f16)(v * s);
  } else {
    int j = i - 384 * 256;
    if (j < 512 * 512) {
      int r = j >> 9, c = j & 511;
      float v = (c < 256) ? wo[r * 256 + c] * (gamma[0] * s * is2)
                          : wr[r * 256 + (c - 256)] * (s * is2);
      int og = r >> 4, lr = r & 15, kc = c >> 5, h2 = (c >> 3) & 3, e = c & 7;
      WcatP[(((og * 16 + kc) * 64 + h2 * 16 + lr) << 3) + e] = (f16)v;
    }
  }
}

// -------------------------------------------------------------------------
// Transpose x [b][256][4096] fp32 -> xT [b][4096][256] fp16 via 64x64 LDS tiles.
__global__ __launch_bounds__(256, 4)
void k_transpose(const float* __restrict__ x, f16* __restrict__ xT) {
  __shared__ f16 tile[64 * 72];
  int b = blockIdx.z, nt = blockIdx.y, ct = blockIdx.x;
  int t = threadIdx.x;
  {
    int c = t >> 2, nch = (t & 3) * 16;
    const float* src = x + (((size_t)b * 256 + ct * 64 + c) << 12) + nt * 64 + nch;
    float4 v0 = *(const float4*)(src);
    float4 v1 = *(const float4*)(src + 4);
    float4 v2 = *(const float4*)(src + 8);
    float4 v3 = *(const float4*)(src + 12);
    f16x8 a = {(f16)v0.x, (f16)v0.y, (f16)v0.z, (f16)v0.w,
               (f16)v1.x, (f16)v1.y, (f16)v1.z, (f16)v1.w};
    f16x8 bb = {(f16)v2.x, (f16)v2.y, (f16)v2.z, (f16)v2.w,
                (f16)v3.x, (f16)v3.y, (f16)v3.z, (f16)v3.w};
    *(f16x8*)&tile[c * 72 + nch] = a;
    *(f16x8*)&tile[c * 72 + nch + 8] = bb;
  }
  __syncthreads();
  {
    int n = t >> 2, cch = (t & 3) * 16;
    f16 tmp[16];
#pragma unroll
    for (int i = 0; i < 16; i++) tmp[i] = tile[(cch + i) * 72 + n];
    f16x8 a, bb;
#pragma unroll
    for (int i = 0; i < 8; i++) { a[i] = tmp[i]; bb[i] = tmp[8 + i]; }
    f16* dst = xT + (((size_t)b * 4096 + nt * 64 + n) << 8) + ct * 64 + cch;
    *(f16x8*)dst = a;
    *(f16x8*)(dst + 8) = bb;
  }
}

// -------------------------------------------------------------------------
// Merged projection GEMM + fused 2x2 maxpool epilogue.
__global__ __launch_bounds__(256, 2)
void k_gemm_projq(const f16* __restrict__ xT, const f16* __restrict__ Wproj,
                  f16* __restrict__ Q, f16* __restrict__ Kp, f16* __restrict__ V) {
  __shared__ f16 lds[192 * 64];  // Alds [64*64] | Blds [128*64]; pool aliases
  f16* Alds = lds;
  f16* Blds = lds + 64 * 64;
  int b = blockIdx.z, mt = blockIdx.y, nt = blockIdx.x;
  int tid = threadIdx.x;
  int lane = tid & 63, wave = tid >> 6;
  int wm = wave >> 1, wn = wave & 1;
  int l15 = lane & 15, hi = lane >> 4;
  f32x4 acc[2][4];
#pragma unroll
  for (int mf = 0; mf < 2; mf++)
#pragma unroll
    for (int nf = 0; nf < 4; nf++) acc[mf][nf] = (f32x4){0, 0, 0, 0};
  const f16* Abase = Wproj + ((mt * 64) << 8);
  const f16* Bbase = xT + (((size_t)b * 4096 + nt * 128) << 8);
  for (int k0 = 0; k0 < 256; k0 += 64) {
    __syncthreads();
#pragma unroll
    for (int i = 0; i < 2; i++) {
      int chunk = i * 256 + tid;
      int row = chunk >> 3, cc = chunk & 7, scc = cc ^ (row & 7);
      gload16(Abase + (row << 8) + k0 + scc * 8, (char*)Alds + (i * 256 + wave * 64) * 16);
    }
#pragma unroll
    for (int i = 0; i < 4; i++) {
      int chunk = i * 256 + tid;
      int row = chunk >> 3, cc = chunk & 7, scc = cc ^ (row & 7);
      gload16(Bbase + (row << 8) + k0 + scc * 8, (char*)Blds + (i * 256 + wave * 64) * 16);
    }
    __syncthreads();
#pragma unroll
    for (int ks = 0; ks < 2; ks++) {
      int cb = (hi * 8 + ks * 32) * 2;
      f16x8 af[2], bf[4];
#pragma unroll
      for (int mf = 0; mf < 2; mf++) {
        int row = wm * 32 + mf * 16 + l15;
        af[mf] = *(const f16x8*)((const char*)Alds + row * 128 + (cb ^ ((row & 7) << 4)));
      }
#pragma unroll
      for (int nf = 0; nf < 4; nf++) {
        int row = wn * 64 + nf * 16 + l15;
        bf[nf] = *(const f16x8*)((const char*)Blds + row * 128 + (cb ^ ((row & 7) << 4)));
      }
#pragma unroll
      for (int mf = 0; mf < 2; mf++)
#pragma unroll
        for (int nf = 0; nf < 4; nf++) acc[mf][nf] = MFMA16(af[mf], bf[nf], acc[mf][nf]);
    }
  }
  if (mt == 0) {
#pragma unroll
    for (int mf = 0; mf < 2; mf++)
#pragma unroll
      for (int nf = 0; nf < 4; nf++)
#pragma unroll
        for (int r = 0; r < 4; r++) {
          int jl = wm * 32 + mf * 16 + hi * 4 + r;
          int n = nt * 128 + wn * 64 + nf * 16 + l15;
          Q[(((size_t)b * 4096 + n) << 6) + jl] = (f16)acc[mf][nf][r];
        }
  } else {
    __syncthreads();  // done reading Alds/Blds
    f16* Pool = lds;
#pragma unroll
    for (int mf = 0; mf < 2; mf++)
#pragma unroll
      for (int nf = 0; nf < 4; nf++)
#pragma unroll
        for (int r = 0; r < 4; r++) {
          int jl = wm * 32 + mf * 16 + hi * 4 + r;
          int col = wn * 64 + nf * 16 + l15;
          Pool[jl * 132 + col] = (f16)acc[mf][nf][r];
        }
    __syncthreads();
    if (mt == 1) {
      int m_l = tid >> 3;
      int jj8 = (tid & 7) * 8;
      f16x8 w;
#pragma unroll
      for (int i = 0; i < 8; i++) {
        int jj = jj8 + i;
        f16x2 p0 = *(const f16x2*)&Pool[jj * 132 + 2 * m_l];
        f16x2 p1 = *(const f16x2*)&Pool[jj * 132 + 64 + 2 * m_l];
        float v = fmaxf(fmaxf((float)p0[0], (float)p0[1]),
                        fmaxf((float)p1[0], (float)p1[1]));
        w[i] = (f16)v;
      }
      *(f16x8*)&Kp[((size_t)b * 1024 + nt * 32 + m_l) * 64 + jj8] = w;
    } else {
      int ch_l = tid >> 2;
      int m8 = (tid & 3) * 8;
      f16x8 w;
#pragma unroll
      for (int i = 0; i < 8; i++) {
        int mm = m8 + i;
        f16x2 p0 = *(const f16x2*)&Pool[ch_l * 132 + 2 * mm];
        f16x2 p1 = *(const f16x2*)&Pool[ch_l * 132 + 64 + 2 * mm];
        float v = fmaxf(fmaxf((float)p0[0], (float)p0[1]),
                        fmaxf((float)p1[0], (float)p1[1]));
        w[i] = (f16)v;
      }
      int ch = (mt - 2) * 64 + ch_l;
      *(f16x8*)&V[(((size_t)b * 256 + ch) << 10) + nt * 32 + m8] = w;
    }
  }
}

// -------------------------------------------------------------------------
// Flash attention + fused output GEMM (two-half epilogue, no spill).
__global__ __launch_bounds__(512, 4)
void k_flash(const f16* __restrict__ Q, const f16* __restrict__ Kp,
             const f16* __restrict__ V, const f16* __restrict__ xT,
             const f16* __restrict__ WcatP, float* __restrict__ out) {
  __shared__ char smem[65536];
  f16* Klds = (f16*)smem;              // 8KB  [key][ch] swizzled
  f16* Vlds = (f16*)(smem + 8192);     // 32KB [ch][key] swizzled
  f16* PldsB = (f16*)(smem + 40960);   // 9.2KB: 4 rg-slots x 16 x 72
  int b = blockIdx.y, qt = blockIdx.x;
  int tid = threadIdx.x;
  int lane = tid & 63, wave = tid >> 6;   // 8 waves
  int rg = wave >> 1, cg2 = wave & 1;     // row-group 0..3 (16q), ch-group 0..1
  int l15 = lane & 15, hi = lane >> 4;
  const f16* Kb = Kp + ((size_t)b << 16);
  const f16* Vb = V + ((size_t)b << 18);
  f16* Pw = PldsB + rg * 16 * 72;  // shared across the cg2 pair
  const float L2E = 1.44269504f;
  int krow_s = tid >> 3, kcc = tid & 7;
  int kscc = kcc ^ (krow_s & 7);
  const f16* kp_src = Kb + (krow_s << 6) + kscc * 8;   // + kt*64*64
  f16* kp_dst = &Klds[tid * 8];
  const f16* vp_src[4];
  f16* vp_dst[4];
#pragma unroll
  for (int i = 0; i < 4; i++) {
    int chunk = i * 512 + tid;
    int row = chunk >> 3, cc = chunk & 7, scc = cc ^ (row & 7);
    vp_src[i] = Vb + ((size_t)row << 10) + scc * 8;    // + kt*64
    vp_dst[i] = &Vlds[chunk * 8];
  }
  f16x8 qf[2];
#pragma unroll
  for (int ks = 0; ks < 2; ks++)
    qf[ks] = *(const f16x8*)(
        Q + (((size_t)b * 4096 + qt * 64 + rg * 16 + l15) << 6) + ks * 32 + hi * 8);
  f32x4 o[8];
#pragma unroll
  for (int i = 0; i < 8; i++) o[i] = (f32x4){0, 0, 0, 0};
  float mrow = -1e30f, lrow = 0.f;

  int cbase = hi * 16;

  f16x8 kreg, vreg0, vreg1, vreg2, vreg3;
  kreg = *(const f16x8*)(kp_src);
  vreg0 = *(const f16x8*)(vp_src[0]);
  vreg1 = *(const f16x8*)(vp_src[1]);
  vreg2 = *(const f16x8*)(vp_src[2]);
  vreg3 = *(const f16x8*)(vp_src[3]);
  *(f16x8*)kp_dst = kreg;
  *(f16x8*)vp_dst[0] = vreg0;
  *(f16x8*)vp_dst[1] = vreg1;
  *(f16x8*)vp_dst[2] = vreg2;
  *(f16x8*)vp_dst[3] = vreg3;
  __syncthreads();

  for (int kt = 0; kt < 16; ++kt) {
    if (kt < 15) {
      kreg = *(const f16x8*)(kp_src + ((kt + 1) << 12));
      vreg0 = *(const f16x8*)(vp_src[0] + ((kt + 1) << 6));
      vreg1 = *(const f16x8*)(vp_src[1] + ((kt + 1) << 6));
      vreg2 = *(const f16x8*)(vp_src[2] + ((kt + 1) << 6));
      vreg3 = *(const f16x8*)(vp_src[3] + ((kt + 1) << 6));
    }
    f32x4 s[4];
#pragma unroll
    for (int mf = 0; mf < 4; mf++) s[mf] = (f32x4){0, 0, 0, 0};
#pragma unroll
    for (int ks = 0; ks < 2; ks++) {
      f16x8 kf[4];
#pragma unroll
      for (int mf = 0; mf < 4; mf++) {
        int row = mf * 16 + l15;
        kf[mf] = *(const f16x8*)((const char*)Klds + row * 128 +
                                 ((cbase + ks * 64) ^ ((row & 7) << 4)));
      }
#pragma unroll
      for (int mf = 0; mf < 4; mf++) s[mf] = MFMA16(kf[mf], qf[ks], s[mf]);
    }
    float t0 = fmaxf(fmaxf(s[0][0], s[1][0]), fmaxf(s[2][0], s[3][0]));
    float t1 = fmaxf(fmaxf(s[0][1], s[1][1]), fmaxf(s[2][1], s[3][1]));
    float t2 = fmaxf(fmaxf(s[0][2], s[1][2]), fmaxf(s[2][2], s[3][2]));
    float t3 = fmaxf(fmaxf(s[0][3], s[1][3]), fmaxf(s[2][3], s[3][3]));
    float mx = fmaxf(fmaxf(t0, t1), fmaxf(t2, t3));
    mx = fmaxf(mx, __shfl_xor(mx, 16, 64));
    mx = fmaxf(mx, __shfl_xor(mx, 32, 64));
    if (__any(mx > mrow + 8.f)) {
      float mnew = fmaxf(mrow, mx);
      float corr = __builtin_amdgcn_exp2f((mrow - mnew) * L2E);
      lrow *= corr;
      mrow = mnew;
#pragma unroll
      for (int r = 0; r < 4; r++) {
        float cr = __shfl(corr, (hi << 4) + (hi << 2) + r, 64);
#pragma unroll
        for (int cf = 0; cf < 8; cf++) o[cf][r] *= cr;
      }
    }
    {
      float e[4][4];
#pragma unroll
      for (int mf = 0; mf < 4; mf++)
#pragma unroll
        for (int r = 0; r < 4; r++)
          e[mf][r] = __builtin_amdgcn_exp2f((s[mf][r] - mrow) * L2E);
#pragma unroll
      for (int mf = 0; mf < 4; mf++) {
        f16x4 w = {(f16)e[mf][0], (f16)e[mf][1], (f16)e[mf][2], (f16)e[mf][3]};
        *(f16x4*)((char*)Pw + l15 * 144 + mf * 32 + hi * 8) = w;
      }
      float u0 = (e[0][0] + e[1][0]) + (e[2][0] + e[3][0]);
      float u1 = (e[0][1] + e[1][1]) + (e[2][1] + e[3][1]);
      float u2 = (e[0][2] + e[1][2]) + (e[2][2] + e[3][2]);
      float u3 = (e[0][3] + e[1][3]) + (e[2][3] + e[3][3]);
      float sum = (u0 + u1) + (u2 + u3);
      sum += __shfl_xor(sum, 16, 64);
      sum += __shfl_xor(sum, 32, 64);
      lrow += sum;
    }
#pragma unroll
    for (int ks = 0; ks < 2; ks++) {
      f16x8 af = *(const f16x8*)((char*)Pw + l15 * 144 + ks * 64 + hi * 16);
      __builtin_amdgcn_s_setprio(1);
#pragma unroll
      for (int cg = 0; cg < 2; cg++) {
        f16x8 vf[4];
#pragma unroll
        for (int u = 0; u < 4; u++) {
          int row = (cg2 * 8 + cg * 4 + u) * 16 + l15;
          vf[u] = *(const f16x8*)((const char*)Vlds + row * 128 +
                                  ((cbase + ks * 64) ^ ((row & 7) << 4)));
        }
#pragma unroll
        for (int u = 0; u < 4; u++) o[cg * 4 + u] = MFMA16(af, vf[u], o[cg * 4 + u]);
      }
      __builtin_amdgcn_s_setprio(0);
    }
    if (kt < 15) {
      __syncthreads();
      *(f16x8*)kp_dst = kreg;
      *(f16x8*)vp_dst[0] = vreg0;
      *(f16x8*)vp_dst[1] = vreg1;
      *(f16x8*)vp_dst[2] = vreg2;
      *(f16x8*)vp_dst[3] = vreg3;
      __syncthreads();
    }
  }

  // ================= fused output GEMM epilogue (two halves) =================
  __syncthreads();  // everyone done with K/V/P reads; smem repurposed
  f16* attT = (f16*)smem;            // [64n][256c] swizzled, 32KB
  f16* xTT = (f16*)(smem + 32768);   // [64n][256k] swizzled, 32KB
#pragma unroll
  for (int i = 0; i < 4; i++) {
    int chunk = i * 512 + tid;
    int row = chunk >> 5, cc = chunk & 31, scc = cc ^ (row & 7);
    gload16(xT + (((size_t)b * 4096 + qt * 64 + row) << 8) + scc * 8,
            (char*)xTT + chunk * 16);
  }
  {
    float inv = 1.f / lrow;
    int nb = rg * 16 + hi * 4;
#pragma unroll
    for (int r = 0; r < 4; r++) {
      float iv = __shfl(inv, (hi << 4) + (hi << 2) + r, 64);
      int n = nb + r;
#pragma unroll
      for (int cf = 0; cf < 8; cf++) {
        int c = cg2 * 128 + cf * 16 + l15;
        *(f16*)((char*)attT + n * 512 + ((c * 2) ^ ((n & 7) << 4))) =
            (f16)(o[cf][r] * iv);
      }
    }
  }
  __syncthreads();  // attT written, xTT staged
#pragma unroll 1
  for (int half = 0; half < 2; ++half) {
    f32x4 acc2[2][4];
#pragma unroll
    for (int mf = 0; mf < 2; mf++)
#pragma unroll
      for (int nf = 0; nf < 4; nf++) acc2[mf][nf] = (f32x4){0, 0, 0, 0};
    for (int kc = 0; kc < 16; ++kc) {
      const char* tile = (kc < 8) ? (const char*)attT : (const char*)xTT;
      int ub = (kc & 7) * 64 + hi * 16;
      f16x8 af[2], bf[4];
#pragma unroll
      for (int mf = 0; mf < 2; mf++)
        af[mf] = *(const f16x8*)(
            WcatP + ((size_t)(((wave * 4 + half * 2 + mf) * 16 + kc) * 64 + lane) << 3));
#pragma unroll
      for (int nf = 0; nf < 4; nf++) {
        int row = nf * 16 + l15;
        bf[nf] = *(const f16x8*)(tile + row * 512 + (ub ^ ((row & 7) << 4)));
      }
#pragma unroll
      for (int mf = 0; mf < 2; mf++)
#pragma unroll
        for (int nf = 0; nf < 4; nf++)
          acc2[mf][nf] = MFMA16(af[mf], bf[nf], acc2[mf][nf]);
    }
#pragma unroll
    for (int mf = 0; mf < 2; mf++)
#pragma unroll
      for (int nf = 0; nf < 4; nf++)
#pragma unroll
        for (int r = 0; r < 4; r++) {
          int oo = wave * 64 + (half * 2 + mf) * 16 + hi * 4 + r;
          int n = qt * 64 + nf * 16 + l15;
          out[(((size_t)b * 512 + oo) << 12) + n] = acc2[mf][nf][r];
        }
  }
}

// -------------------------------------------------------------------------
extern "C" void kernel_launch(void* const* d_in, const int* in_sizes, int n_in,
                              void* d_out, int out_size, void* d_ws, size_t ws_size,
                              hipStream_t stream) {
  const float* x = (const float*)d_in[0];
  const float* wt = (const float*)d_in[1];
  const float* wp = (const float*)d_in[2];
  const float* wg = (const float*)d_in[3];
  const float* wo = (const float*)d_in[4];
  const float* wr = (const float*)d_in[5];
  const float* gm = (const float*)d_in[6];
  float* out = (float*)d_out;
  char* ws = (char*)d_ws;
  const size_t MB = 1024 * 1024;
  f16* xT = (f16*)(ws);
  f16* Qb = (f16*)(ws + 16 * MB);
  f16* Kp = (f16*)(ws + 20 * MB);
  f16* Vb = (f16*)(ws + 21 * MB);
  f16* Wproj = (f16*)(ws + 25 * MB);
  f16* WcatP = (f16*)(ws + 25 * MB + 512 * 1024);

  hipLaunchKernelGGL(k_prep_w, dim3(1408), dim3(256), 0, stream, wt, wp, wg, wo, wr, gm,
                     Wproj, WcatP);
  hipLaunchKernelGGL(k_transpose, dim3(4, 64, 8), dim3(256), 0, stream, x, xT);
  hipLaunchKernelGGL(k_gemm_projq, dim3(32, 6, 8), dim3(256), 0, stream, xT, Wproj, Qb,
                     Kp, Vb);
  hipLaunchKernelGGL(k_flash, dim3(64, 8), dim3(512), 0, stream, Qb, Kp, Vb, xT, WcatP,
                     out);
}

// Round 19
// 98.479 us; speedup vs baseline: 2.4239x; 2.4239x over previous
//
#include <hip/hip_runtime.h>

// NonLocalBlock (SAGAN non-local) fused pipeline for MI355X / gfx950.
// B=8, Cin=256, H=W=64 (HW=4096), Cout=512. Workspace (~46 MB of d_ws):
//   [0,16MB)   xT    fp16 [8][4096][256]
//   [16,20MB)  Q     fp16 [8][4096][64]
//   [20,21MB)  Kp    fp16 [8][1024][64]
//   [21,25MB)  V     fp16 [8][256][1024]
//   [25MB+0)   Wproj fp16 [384][256]
//   [25MB+512K) WcatP fp16 [512][512] fragment-permuted
//
// R18->R19: R18's unroll-1 epilogue split perturbed GLOBAL regalloc ->
// main-loop state spilled per-kt (470MB scratch, 218us). Reverted to the
// R17 kernel with ONE change: main loop staging back to gload16
// direct-to-LDS (R15 structure, measured 50.2us standalone) instead of
// T14 reg-staging. That frees ~40 arch VGPRs so the (unchanged, single
// region) R17 epilogue no longer fights the main loop for registers.
// T14 was only worth ~1us; the spill costs ~10.

typedef _Float16 f16;
typedef f16 f16x2 __attribute__((ext_vector_type(2)));
typedef f16 f16x4 __attribute__((ext_vector_type(4)));
typedef f16 f16x8 __attribute__((ext_vector_type(8)));
typedef float f32x4 __attribute__((ext_vector_type(4)));

#define MFMA16(a, b, c) __builtin_amdgcn_mfma_f32_16x16x32_f16((a), (b), (c), 0, 0, 0)

__device__ __forceinline__ void gload16(const void* src, void* dst_lds) {
  __builtin_amdgcn_global_load_lds(
      (const __attribute__((address_space(1))) void*)src,
      (__attribute__((address_space(3))) void*)dst_lds, 16, 0, 0);
}

// -------------------------------------------------------------------------
// Weight prep. Wproj as before. WcatP fragment-permuted:
//   Wcat[r][c] -> WcatP[(((r>>4)*16 + (c>>5))*64 + ((c>>3)&3)*16 + (r&15))*8 + (c&7)]
__global__ __launch_bounds__(256, 4)
void k_prep_w(const float* __restrict__ wt, const float* __restrict__ wp,
              const float* __restrict__ wg, const float* __restrict__ wo,
              const float* __restrict__ wr, const float* __restrict__ gamma,
              f16* __restrict__ Wproj, f16* __restrict__ WcatP) {
  int i = blockIdx.x * 256 + threadIdx.x;
  const float s = 0.08838834764831845f;    // sqrt(2/256)
  const float is2 = 0.7071067811865476f;   // 1/sqrt(2)
  if (i < 384 * 256) {
    float v = (i < 64 * 256) ? wt[i]
              : (i < 128 * 256 ? wp[i - 64 * 256] : wg[i - 128 * 256]);
    Wproj[i] = (f16)(v * s);
  } else {
    int j = i - 384 * 256;
    if (j < 512 * 512) {
      int r = j >> 9, c = j & 511;
      float v = (c < 256) ? wo[r * 256 + c] * (gamma[0] * s * is2)
                          : wr[r * 256 + (c - 256)] * (s * is2);
      int og = r >> 4, lr = r & 15, kc = c >> 5, h2 = (c >> 3) & 3, e = c & 7;
      WcatP[(((og * 16 + kc) * 64 + h2 * 16 + lr) << 3) + e] = (f16)v;
    }
  }
}

// -------------------------------------------------------------------------
// Transpose x [b][256][4096] fp32 -> xT [b][4096][256] fp16 via 64x64 LDS tiles.
__global__ __launch_bounds__(256, 4)
void k_transpose(const float* __restrict__ x, f16* __restrict__ xT) {
  __shared__ f16 tile[64 * 72];
  int b = blockIdx.z, nt = blockIdx.y, ct = blockIdx.x;
  int t = threadIdx.x;
  {
    int c = t >> 2, nch = (t & 3) * 16;
    const float* src = x + (((size_t)b * 256 + ct * 64 + c) << 12) + nt * 64 + nch;
    float4 v0 = *(const float4*)(src);
    float4 v1 = *(const float4*)(src + 4);
    float4 v2 = *(const float4*)(src + 8);
    float4 v3 = *(const float4*)(src + 12);
    f16x8 a = {(f16)v0.x, (f16)v0.y, (f16)v0.z, (f16)v0.w,
               (f16)v1.x, (f16)v1.y, (f16)v1.z, (f16)v1.w};
    f16x8 bb = {(f16)v2.x, (f16)v2.y, (f16)v2.z, (f16)v2.w,
                (f16)v3.x, (f16)v3.y, (f16)v3.z, (f16)v3.w};
    *(f16x8*)&tile[c * 72 + nch] = a;
    *(f16x8*)&tile[c * 72 + nch + 8] = bb;
  }
  __syncthreads();
  {
    int n = t >> 2, cch = (t & 3) * 16;
    f16 tmp[16];
#pragma unroll
    for (int i = 0; i < 16; i++) tmp[i] = tile[(cch + i) * 72 + n];
    f16x8 a, bb;
#pragma unroll
    for (int i = 0; i < 8; i++) { a[i] = tmp[i]; bb[i] = tmp[8 + i]; }
    f16* dst = xT + (((size_t)b * 4096 + nt * 64 + n) << 8) + ct * 64 + cch;
    *(f16x8*)dst = a;
    *(f16x8*)(dst + 8) = bb;
  }
}

// -------------------------------------------------------------------------
// Merged projection GEMM + fused 2x2 maxpool epilogue.
__global__ __launch_bounds__(256, 2)
void k_gemm_projq(const f16* __restrict__ xT, const f16* __restrict__ Wproj,
                  f16* __restrict__ Q, f16* __restrict__ Kp, f16* __restrict__ V) {
  __shared__ f16 lds[192 * 64];  // Alds [64*64] | Blds [128*64]; pool aliases
  f16* Alds = lds;
  f16* Blds = lds + 64 * 64;
  int b = blockIdx.z, mt = blockIdx.y, nt = blockIdx.x;
  int tid = threadIdx.x;
  int lane = tid & 63, wave = tid >> 6;
  int wm = wave >> 1, wn = wave & 1;
  int l15 = lane & 15, hi = lane >> 4;
  f32x4 acc[2][4];
#pragma unroll
  for (int mf = 0; mf < 2; mf++)
#pragma unroll
    for (int nf = 0; nf < 4; nf++) acc[mf][nf] = (f32x4){0, 0, 0, 0};
  const f16* Abase = Wproj + ((mt * 64) << 8);
  const f16* Bbase = xT + (((size_t)b * 4096 + nt * 128) << 8);
  for (int k0 = 0; k0 < 256; k0 += 64) {
    __syncthreads();
#pragma unroll
    for (int i = 0; i < 2; i++) {
      int chunk = i * 256 + tid;
      int row = chunk >> 3, cc = chunk & 7, scc = cc ^ (row & 7);
      gload16(Abase + (row << 8) + k0 + scc * 8, (char*)Alds + (i * 256 + wave * 64) * 16);
    }
#pragma unroll
    for (int i = 0; i < 4; i++) {
      int chunk = i * 256 + tid;
      int row = chunk >> 3, cc = chunk & 7, scc = cc ^ (row & 7);
      gload16(Bbase + (row << 8) + k0 + scc * 8, (char*)Blds + (i * 256 + wave * 64) * 16);
    }
    __syncthreads();
#pragma unroll
    for (int ks = 0; ks < 2; ks++) {
      int cb = (hi * 8 + ks * 32) * 2;
      f16x8 af[2], bf[4];
#pragma unroll
      for (int mf = 0; mf < 2; mf++) {
        int row = wm * 32 + mf * 16 + l15;
        af[mf] = *(const f16x8*)((const char*)Alds + row * 128 + (cb ^ ((row & 7) << 4)));
      }
#pragma unroll
      for (int nf = 0; nf < 4; nf++) {
        int row = wn * 64 + nf * 16 + l15;
        bf[nf] = *(const f16x8*)((const char*)Blds + row * 128 + (cb ^ ((row & 7) << 4)));
      }
#pragma unroll
      for (int mf = 0; mf < 2; mf++)
#pragma unroll
        for (int nf = 0; nf < 4; nf++) acc[mf][nf] = MFMA16(af[mf], bf[nf], acc[mf][nf]);
    }
  }
  if (mt == 0) {
#pragma unroll
    for (int mf = 0; mf < 2; mf++)
#pragma unroll
      for (int nf = 0; nf < 4; nf++)
#pragma unroll
        for (int r = 0; r < 4; r++) {
          int jl = wm * 32 + mf * 16 + hi * 4 + r;
          int n = nt * 128 + wn * 64 + nf * 16 + l15;
          Q[(((size_t)b * 4096 + n) << 6) + jl] = (f16)acc[mf][nf][r];
        }
  } else {
    __syncthreads();  // done reading Alds/Blds
    f16* Pool = lds;
#pragma unroll
    for (int mf = 0; mf < 2; mf++)
#pragma unroll
      for (int nf = 0; nf < 4; nf++)
#pragma unroll
        for (int r = 0; r < 4; r++) {
          int jl = wm * 32 + mf * 16 + hi * 4 + r;
          int col = wn * 64 + nf * 16 + l15;
          Pool[jl * 132 + col] = (f16)acc[mf][nf][r];
        }
    __syncthreads();
    if (mt == 1) {
      int m_l = tid >> 3;
      int jj8 = (tid & 7) * 8;
      f16x8 w;
#pragma unroll
      for (int i = 0; i < 8; i++) {
        int jj = jj8 + i;
        f16x2 p0 = *(const f16x2*)&Pool[jj * 132 + 2 * m_l];
        f16x2 p1 = *(const f16x2*)&Pool[jj * 132 + 64 + 2 * m_l];
        float v = fmaxf(fmaxf((float)p0[0], (float)p0[1]),
                        fmaxf((float)p1[0], (float)p1[1]));
        w[i] = (f16)v;
      }
      *(f16x8*)&Kp[((size_t)b * 1024 + nt * 32 + m_l) * 64 + jj8] = w;
    } else {
      int ch_l = tid >> 2;
      int m8 = (tid & 3) * 8;
      f16x8 w;
#pragma unroll
      for (int i = 0; i < 8; i++) {
        int mm = m8 + i;
        f16x2 p0 = *(const f16x2*)&Pool[ch_l * 132 + 2 * mm];
        f16x2 p1 = *(const f16x2*)&Pool[ch_l * 132 + 64 + 2 * mm];
        float v = fmaxf(fmaxf((float)p0[0], (float)p0[1]),
                        fmaxf((float)p1[0], (float)p1[1]));
        w[i] = (f16)v;
      }
      int ch = (mt - 2) * 64 + ch_l;
      *(f16x8*)&V[(((size_t)b * 256 + ch) << 10) + nt * 32 + m8] = w;
    }
  }
}

// -------------------------------------------------------------------------
// Flash attention + fused output GEMM. Main loop = R15 structure (gload16
// single-buffer, stage-after-compute); epilogue = R17 (single region).
__global__ __launch_bounds__(512, 4)
void k_flash(const f16* __restrict__ Q, const f16* __restrict__ Kp,
             const f16* __restrict__ V, const f16* __restrict__ xT,
             const f16* __restrict__ WcatP, float* __restrict__ out) {
  __shared__ char smem[65536];
  f16* Klds = (f16*)smem;              // 8KB  [key][ch] swizzled
  f16* Vlds = (f16*)(smem + 8192);     // 32KB [ch][key] swizzled
  f16* PldsB = (f16*)(smem + 40960);   // 9.2KB: 4 rg-slots x 16 x 72
  int b = blockIdx.y, qt = blockIdx.x;
  int tid = threadIdx.x;
  int lane = tid & 63, wave = tid >> 6;   // 8 waves
  int rg = wave >> 1, cg2 = wave & 1;     // row-group 0..3 (16q), ch-group 0..1
  int l15 = lane & 15, hi = lane >> 4;
  const f16* Kb = Kp + ((size_t)b << 16);
  const f16* Vb = V + ((size_t)b << 18);
  f16* Pw = PldsB + rg * 16 * 72;  // shared across the cg2 pair
  const float L2E = 1.44269504f;
  f16x8 qf[2];
#pragma unroll
  for (int ks = 0; ks < 2; ks++)
    qf[ks] = *(const f16x8*)(
        Q + (((size_t)b * 4096 + qt * 64 + rg * 16 + l15) << 6) + ks * 32 + hi * 8);
  f32x4 o[8];
#pragma unroll
  for (int i = 0; i < 8; i++) o[i] = (f32x4){0, 0, 0, 0};
  float mrow = -1e30f, lrow = 0.f;

  int cbase = hi * 16;

#define STAGE(kt)                                                                \
  {                                                                              \
    {                                                                            \
      int chunk = tid;                                                           \
      int row = chunk >> 3, cc = chunk & 7, scc = cc ^ (row & 7);                \
      gload16(Kb + (((kt) * 64 + row) << 6) + scc * 8,                           \
              (char*)Klds + chunk * 16);                                         \
    }                                                                            \
    _Pragma("unroll") for (int i = 0; i < 4; i++) {                              \
      int chunk = i * 512 + tid;                                                 \
      int row = chunk >> 3, cc = chunk & 7, scc = cc ^ (row & 7);                \
      gload16(Vb + ((size_t)row << 10) + (kt) * 64 + scc * 8,                    \
              (char*)Vlds + chunk * 16);                                         \
    }                                                                            \
  }

  STAGE(0);
  __syncthreads();
  for (int kt = 0; kt < 16; ++kt) {
    // ---- S^T = K Q^T: lane holds q-row l15, keys mf*16+hi*4+r
    f32x4 s[4];
#pragma unroll
    for (int mf = 0; mf < 4; mf++) s[mf] = (f32x4){0, 0, 0, 0};
#pragma unroll
    for (int ks = 0; ks < 2; ks++) {
      f16x8 kf[4];
#pragma unroll
      for (int mf = 0; mf < 4; mf++) {
        int row = mf * 16 + l15;
        kf[mf] = *(const f16x8*)((const char*)Klds + row * 128 +
                                 ((cbase + ks * 64) ^ ((row & 7) << 4)));
      }
#pragma unroll
      for (int mf = 0; mf < 4; mf++) s[mf] = MFMA16(kf[mf], qf[ks], s[mf]);
    }
    // ---- lane-local online softmax (defer-max THR=8)
    float t0 = fmaxf(fmaxf(s[0][0], s[1][0]), fmaxf(s[2][0], s[3][0]));
    float t1 = fmaxf(fmaxf(s[0][1], s[1][1]), fmaxf(s[2][1], s[3][1]));
    float t2 = fmaxf(fmaxf(s[0][2], s[1][2]), fmaxf(s[2][2], s[3][2]));
    float t3 = fmaxf(fmaxf(s[0][3], s[1][3]), fmaxf(s[2][3], s[3][3]));
    float mx = fmaxf(fmaxf(t0, t1), fmaxf(t2, t3));
    mx = fmaxf(mx, __shfl_xor(mx, 16, 64));
    mx = fmaxf(mx, __shfl_xor(mx, 32, 64));
    if (__any(mx > mrow + 8.f)) {
      float mnew = fmaxf(mrow, mx);
      float corr = __builtin_amdgcn_exp2f((mrow - mnew) * L2E);
      lrow *= corr;
      mrow = mnew;
#pragma unroll
      for (int r = 0; r < 4; r++) {
        float cr = __shfl(corr, (hi << 4) + (hi << 2) + r, 64);
#pragma unroll
        for (int cf = 0; cf < 8; cf++) o[cf][r] *= cr;
      }
    }
    {
      float e[4][4];
#pragma unroll
      for (int mf = 0; mf < 4; mf++)
#pragma unroll
        for (int r = 0; r < 4; r++)
          e[mf][r] = __builtin_amdgcn_exp2f((s[mf][r] - mrow) * L2E);
#pragma unroll
      for (int mf = 0; mf < 4; mf++) {
        f16x4 w = {(f16)e[mf][0], (f16)e[mf][1], (f16)e[mf][2], (f16)e[mf][3]};
        *(f16x4*)((char*)Pw + l15 * 144 + mf * 32 + hi * 8) = w;
      }
      float u0 = (e[0][0] + e[1][0]) + (e[2][0] + e[3][0]);
      float u1 = (e[0][1] + e[1][1]) + (e[2][1] + e[3][1]);
      float u2 = (e[0][2] + e[1][2]) + (e[2][2] + e[3][2]);
      float u3 = (e[0][3] + e[1][3]) + (e[2][3] + e[3][3]);
      float sum = (u0 + u1) + (u2 + u3);
      sum += __shfl_xor(sum, 16, 64);
      sum += __shfl_xor(sum, 32, 64);
      lrow += sum;
    }
    // ---- PV: this wave covers channels cg2*128 .. cg2*128+127
#pragma unroll
    for (int ks = 0; ks < 2; ks++) {
      f16x8 af = *(const f16x8*)((char*)Pw + l15 * 144 + ks * 64 + hi * 16);
      __builtin_amdgcn_s_setprio(1);
#pragma unroll
      for (int cg = 0; cg < 2; cg++) {
        f16x8 vf[4];
#pragma unroll
        for (int u = 0; u < 4; u++) {
          int row = (cg2 * 8 + cg * 4 + u) * 16 + l15;
          vf[u] = *(const f16x8*)((const char*)Vlds + row * 128 +
                                  ((cbase + ks * 64) ^ ((row & 7) << 4)));
        }
#pragma unroll
        for (int u = 0; u < 4; u++) o[cg * 4 + u] = MFMA16(af, vf[u], o[cg * 4 + u]);
      }
      __builtin_amdgcn_s_setprio(0);
    }
    if (kt < 15) {
      __syncthreads();   // all waves done reading Klds/Vlds (and Plds)
      STAGE(kt + 1);
      __syncthreads();   // staged data visible (vmcnt drain)
    }
  }
#undef STAGE

  // ================= fused output GEMM epilogue (R17, single region) ========
  __syncthreads();  // everyone done with K/V/P reads; smem repurposed
  f16* attT = (f16*)smem;            // [64n][256c] swizzled, 32KB
  f16* xTT = (f16*)(smem + 32768);   // [64n][256k] swizzled, 32KB
#pragma unroll
  for (int i = 0; i < 4; i++) {
    int chunk = i * 512 + tid;
    int row = chunk >> 5, cc = chunk & 31, scc = cc ^ (row & 7);
    gload16(xT + (((size_t)b * 4096 + qt * 64 + row) << 8) + scc * 8,
            (char*)xTT + chunk * 16);
  }
  {
    float inv = 1.f / lrow;
    int nb = rg * 16 + hi * 4;
#pragma unroll
    for (int r = 0; r < 4; r++) {
      float iv = __shfl(inv, (hi << 4) + (hi << 2) + r, 64);
      int n = nb + r;
#pragma unroll
      for (int cf = 0; cf < 8; cf++) {
        int c = cg2 * 128 + cf * 16 + l15;
        *(f16*)((char*)attT + n * 512 + ((c * 2) ^ ((n & 7) << 4))) =
            (f16)(o[cf][r] * iv);
      }
    }
  }
  __syncthreads();  // attT written, xTT staged (vmcnt drained by barrier)
  {
    f32x4 acc2[4][4];
#pragma unroll
    for (int mf = 0; mf < 4; mf++)
#pragma unroll
      for (int nf = 0; nf < 4; nf++) acc2[mf][nf] = (f32x4){0, 0, 0, 0};
    for (int kc = 0; kc < 16; ++kc) {
      const char* tile = (kc < 8) ? (const char*)attT : (const char*)xTT;
      int ub = (kc & 7) * 64 + hi * 16;
      f16x8 af[4], bf[4];
#pragma unroll
      for (int mf = 0; mf < 4; mf++)
        af[mf] = *(const f16x8*)(WcatP +
                                 ((size_t)(((wave * 4 + mf) * 16 + kc) * 64 + lane) << 3));
#pragma unroll
      for (int nf = 0; nf < 4; nf++) {
        int row = nf * 16 + l15;
        bf[nf] = *(const f16x8*)(tile + row * 512 + (ub ^ ((row & 7) << 4)));
      }
#pragma unroll
      for (int mf = 0; mf < 4; mf++)
#pragma unroll
        for (int nf = 0; nf < 4; nf++)
          acc2[mf][nf] = MFMA16(af[mf], bf[nf], acc2[mf][nf]);
    }
#pragma unroll
    for (int mf = 0; mf < 4; mf++)
#pragma unroll
      for (int nf = 0; nf < 4; nf++)
#pragma unroll
        for (int r = 0; r < 4; r++) {
          int oo = wave * 64 + mf * 16 + hi * 4 + r;
          int n = qt * 64 + nf * 16 + l15;
          out[(((size_t)b * 512 + oo) << 12) + n] = acc2[mf][nf][r];
        }
  }
}

// -------------------------------------------------------------------------
extern "C" void kernel_launch(void* const* d_in, const int* in_sizes, int n_in,
                              void* d_out, int out_size, void* d_ws, size_t ws_size,
                              hipStream_t stream) {
  const float* x = (const float*)d_in[0];
  const float* wt = (const float*)d_in[1];
  const float* wp = (const float*)d_in[2];
  const float* wg = (const float*)d_in[3];
  const float* wo = (const float*)d_in[4];
  const float* wr = (const float*)d_in[5];
  const float* gm = (const float*)d_in[6];
  float* out = (float*)d_out;
  char* ws = (char*)d_ws;
  const size_t MB = 1024 * 1024;
  f16* xT = (f16*)(ws);
  f16* Qb = (f16*)(ws + 16 * MB);
  f16* Kp = (f16*)(ws + 20 * MB);
  f16* Vb = (f16*)(ws + 21 * MB);
  f16* Wproj = (f16*)(ws + 25 * MB);
  f16* WcatP = (f16*)(ws + 25 * MB + 512 * 1024);

  hipLaunchKernelGGL(k_prep_w, dim3(1408), dim3(256), 0, stream, wt, wp, wg, wo, wr, gm,
                     Wproj, WcatP);
  hipLaunchKernelGGL(k_transpose, dim3(4, 64, 8), dim3(256), 0, stream, x, xT);
  hipLaunchKernelGGL(k_gemm_projq, dim3(32, 6, 8), dim3(256), 0, stream, xT, Wproj, Qb,
                     Kp, Vb);
  hipLaunchKernelGGL(k_flash, dim3(64, 8), dim3(512), 0, stream, Qb, Kp, Vb, xT, WcatP,
                     out);
}

// Round 20
// 97.768 us; speedup vs baseline: 2.4415x; 1.0073x over previous
//
#include <hip/hip_runtime.h>

// NonLocalBlock (SAGAN non-local) fused pipeline for MI355X / gfx950.
// B=8, Cin=256, H=W=64 (HW=4096), Cout=512. Workspace (~46 MB of d_ws):
//   [0,16MB)   xT    fp16 [8][4096][256]
//   [16,20MB)  Q     fp16 [8][4096][64]
//   [20,21MB)  Kp    fp16 [8][1024][64]
//   [21,25MB)  V     fp16 [8][256][1024]
//   [25MB+0)   Wproj fp16 [384][256]
//   [25MB+512K) WcatP fp16 [512][512] fragment-permuted
//
// R19->R20: the fused kernel is ~12 regs over the 128 cap (FETCH/WRITE
// +12MB each, VGPR squeezed to 64) regardless of T14. Two LOCAL lifetime
// narrowings (instruction content & barriers unchanged):
//  (a) main loop: exp->pack->sum fused PER-MF (4 e-values live, was 16);
//  (b) epilogue: bf loaded one-at-a-time inside the nf loop (af[4]+1 bf
//      live = 24, was 32).
// Unlike R18's loop-split (which rewrote control flow and blew up global
// regalloc), these keep straight-line structure.

typedef _Float16 f16;
typedef f16 f16x2 __attribute__((ext_vector_type(2)));
typedef f16 f16x4 __attribute__((ext_vector_type(4)));
typedef f16 f16x8 __attribute__((ext_vector_type(8)));
typedef float f32x4 __attribute__((ext_vector_type(4)));

#define MFMA16(a, b, c) __builtin_amdgcn_mfma_f32_16x16x32_f16((a), (b), (c), 0, 0, 0)

__device__ __forceinline__ void gload16(const void* src, void* dst_lds) {
  __builtin_amdgcn_global_load_lds(
      (const __attribute__((address_space(1))) void*)src,
      (__attribute__((address_space(3))) void*)dst_lds, 16, 0, 0);
}

// -------------------------------------------------------------------------
// Weight prep. Wproj as before. WcatP fragment-permuted:
//   Wcat[r][c] -> WcatP[(((r>>4)*16 + (c>>5))*64 + ((c>>3)&3)*16 + (r&15))*8 + (c&7)]
__global__ __launch_bounds__(256, 4)
void k_prep_w(const float* __restrict__ wt, const float* __restrict__ wp,
              const float* __restrict__ wg, const float* __restrict__ wo,
              const float* __restrict__ wr, const float* __restrict__ gamma,
              f16* __restrict__ Wproj, f16* __restrict__ WcatP) {
  int i = blockIdx.x * 256 + threadIdx.x;
  const float s = 0.08838834764831845f;    // sqrt(2/256)
  const float is2 = 0.7071067811865476f;   // 1/sqrt(2)
  if (i < 384 * 256) {
    float v = (i < 64 * 256) ? wt[i]
              : (i < 128 * 256 ? wp[i - 64 * 256] : wg[i - 128 * 256]);
    Wproj[i] = (f16)(v * s);
  } else {
    int j = i - 384 * 256;
    if (j < 512 * 512) {
      int r = j >> 9, c = j & 511;
      float v = (c < 256) ? wo[r * 256 + c] * (gamma[0] * s * is2)
                          : wr[r * 256 + (c - 256)] * (s * is2);
      int og = r >> 4, lr = r & 15, kc = c >> 5, h2 = (c >> 3) & 3, e = c & 7;
      WcatP[(((og * 16 + kc) * 64 + h2 * 16 + lr) << 3) + e] = (f16)v;
    }
  }
}

// -------------------------------------------------------------------------
// Transpose x [b][256][4096] fp32 -> xT [b][4096][256] fp16 via 64x64 LDS tiles.
__global__ __launch_bounds__(256, 4)
void k_transpose(const float* __restrict__ x, f16* __restrict__ xT) {
  __shared__ f16 tile[64 * 72];
  int b = blockIdx.z, nt = blockIdx.y, ct = blockIdx.x;
  int t = threadIdx.x;
  {
    int c = t >> 2, nch = (t & 3) * 16;
    const float* src = x + (((size_t)b * 256 + ct * 64 + c) << 12) + nt * 64 + nch;
    float4 v0 = *(const float4*)(src);
    float4 v1 = *(const float4*)(src + 4);
    float4 v2 = *(const float4*)(src + 8);
    float4 v3 = *(const float4*)(src + 12);
    f16x8 a = {(f16)v0.x, (f16)v0.y, (f16)v0.z, (f16)v0.w,
               (f16)v1.x, (f16)v1.y, (f16)v1.z, (f16)v1.w};
    f16x8 bb = {(f16)v2.x, (f16)v2.y, (f16)v2.z, (f16)v2.w,
                (f16)v3.x, (f16)v3.y, (f16)v3.z, (f16)v3.w};
    *(f16x8*)&tile[c * 72 + nch] = a;
    *(f16x8*)&tile[c * 72 + nch + 8] = bb;
  }
  __syncthreads();
  {
    int n = t >> 2, cch = (t & 3) * 16;
    f16 tmp[16];
#pragma unroll
    for (int i = 0; i < 16; i++) tmp[i] = tile[(cch + i) * 72 + n];
    f16x8 a, bb;
#pragma unroll
    for (int i = 0; i < 8; i++) { a[i] = tmp[i]; bb[i] = tmp[8 + i]; }
    f16* dst = xT + (((size_t)b * 4096 + nt * 64 + n) << 8) + ct * 64 + cch;
    *(f16x8*)dst = a;
    *(f16x8*)(dst + 8) = bb;
  }
}

// -------------------------------------------------------------------------
// Merged projection GEMM + fused 2x2 maxpool epilogue.
__global__ __launch_bounds__(256, 2)
void k_gemm_projq(const f16* __restrict__ xT, const f16* __restrict__ Wproj,
                  f16* __restrict__ Q, f16* __restrict__ Kp, f16* __restrict__ V) {
  __shared__ f16 lds[192 * 64];  // Alds [64*64] | Blds [128*64]; pool aliases
  f16* Alds = lds;
  f16* Blds = lds + 64 * 64;
  int b = blockIdx.z, mt = blockIdx.y, nt = blockIdx.x;
  int tid = threadIdx.x;
  int lane = tid & 63, wave = tid >> 6;
  int wm = wave >> 1, wn = wave & 1;
  int l15 = lane & 15, hi = lane >> 4;
  f32x4 acc[2][4];
#pragma unroll
  for (int mf = 0; mf < 2; mf++)
#pragma unroll
    for (int nf = 0; nf < 4; nf++) acc[mf][nf] = (f32x4){0, 0, 0, 0};
  const f16* Abase = Wproj + ((mt * 64) << 8);
  const f16* Bbase = xT + (((size_t)b * 4096 + nt * 128) << 8);
  for (int k0 = 0; k0 < 256; k0 += 64) {
    __syncthreads();
#pragma unroll
    for (int i = 0; i < 2; i++) {
      int chunk = i * 256 + tid;
      int row = chunk >> 3, cc = chunk & 7, scc = cc ^ (row & 7);
      gload16(Abase + (row << 8) + k0 + scc * 8, (char*)Alds + (i * 256 + wave * 64) * 16);
    }
#pragma unroll
    for (int i = 0; i < 4; i++) {
      int chunk = i * 256 + tid;
      int row = chunk >> 3, cc = chunk & 7, scc = cc ^ (row & 7);
      gload16(Bbase + (row << 8) + k0 + scc * 8, (char*)Blds + (i * 256 + wave * 64) * 16);
    }
    __syncthreads();
#pragma unroll
    for (int ks = 0; ks < 2; ks++) {
      int cb = (hi * 8 + ks * 32) * 2;
      f16x8 af[2], bf[4];
#pragma unroll
      for (int mf = 0; mf < 2; mf++) {
        int row = wm * 32 + mf * 16 + l15;
        af[mf] = *(const f16x8*)((const char*)Alds + row * 128 + (cb ^ ((row & 7) << 4)));
      }
#pragma unroll
      for (int nf = 0; nf < 4; nf++) {
        int row = wn * 64 + nf * 16 + l15;
        bf[nf] = *(const f16x8*)((const char*)Blds + row * 128 + (cb ^ ((row & 7) << 4)));
      }
#pragma unroll
      for (int mf = 0; mf < 2; mf++)
#pragma unroll
        for (int nf = 0; nf < 4; nf++) acc[mf][nf] = MFMA16(af[mf], bf[nf], acc[mf][nf]);
    }
  }
  if (mt == 0) {
#pragma unroll
    for (int mf = 0; mf < 2; mf++)
#pragma unroll
      for (int nf = 0; nf < 4; nf++)
#pragma unroll
        for (int r = 0; r < 4; r++) {
          int jl = wm * 32 + mf * 16 + hi * 4 + r;
          int n = nt * 128 + wn * 64 + nf * 16 + l15;
          Q[(((size_t)b * 4096 + n) << 6) + jl] = (f16)acc[mf][nf][r];
        }
  } else {
    __syncthreads();  // done reading Alds/Blds
    f16* Pool = lds;
#pragma unroll
    for (int mf = 0; mf < 2; mf++)
#pragma unroll
      for (int nf = 0; nf < 4; nf++)
#pragma unroll
        for (int r = 0; r < 4; r++) {
          int jl = wm * 32 + mf * 16 + hi * 4 + r;
          int col = wn * 64 + nf * 16 + l15;
          Pool[jl * 132 + col] = (f16)acc[mf][nf][r];
        }
    __syncthreads();
    if (mt == 1) {
      int m_l = tid >> 3;
      int jj8 = (tid & 7) * 8;
      f16x8 w;
#pragma unroll
      for (int i = 0; i < 8; i++) {
        int jj = jj8 + i;
        f16x2 p0 = *(const f16x2*)&Pool[jj * 132 + 2 * m_l];
        f16x2 p1 = *(const f16x2*)&Pool[jj * 132 + 64 + 2 * m_l];
        float v = fmaxf(fmaxf((float)p0[0], (float)p0[1]),
                        fmaxf((float)p1[0], (float)p1[1]));
        w[i] = (f16)v;
      }
      *(f16x8*)&Kp[((size_t)b * 1024 + nt * 32 + m_l) * 64 + jj8] = w;
    } else {
      int ch_l = tid >> 2;
      int m8 = (tid & 3) * 8;
      f16x8 w;
#pragma unroll
      for (int i = 0; i < 8; i++) {
        int mm = m8 + i;
        f16x2 p0 = *(const f16x2*)&Pool[ch_l * 132 + 2 * mm];
        f16x2 p1 = *(const f16x2*)&Pool[ch_l * 132 + 64 + 2 * mm];
        float v = fmaxf(fmaxf((float)p0[0], (float)p0[1]),
                        fmaxf((float)p1[0], (float)p1[1]));
        w[i] = (f16)v;
      }
      int ch = (mt - 2) * 64 + ch_l;
      *(f16x8*)&V[(((size_t)b * 256 + ch) << 10) + nt * 32 + m8] = w;
    }
  }
}

// -------------------------------------------------------------------------
// Flash attention + fused output GEMM (lifetime-narrowed, no spill).
__global__ __launch_bounds__(512, 4)
void k_flash(const f16* __restrict__ Q, const f16* __restrict__ Kp,
             const f16* __restrict__ V, const f16* __restrict__ xT,
             const f16* __restrict__ WcatP, float* __restrict__ out) {
  __shared__ char smem[65536];
  f16* Klds = (f16*)smem;              // 8KB  [key][ch] swizzled
  f16* Vlds = (f16*)(smem + 8192);     // 32KB [ch][key] swizzled
  f16* PldsB = (f16*)(smem + 40960);   // 9.2KB: 4 rg-slots x 16 x 72
  int b = blockIdx.y, qt = blockIdx.x;
  int tid = threadIdx.x;
  int lane = tid & 63, wave = tid >> 6;   // 8 waves
  int rg = wave >> 1, cg2 = wave & 1;     // row-group 0..3 (16q), ch-group 0..1
  int l15 = lane & 15, hi = lane >> 4;
  const f16* Kb = Kp + ((size_t)b << 16);
  const f16* Vb = V + ((size_t)b << 18);
  f16* Pw = PldsB + rg * 16 * 72;  // shared across the cg2 pair
  const float L2E = 1.44269504f;
  f16x8 qf[2];
#pragma unroll
  for (int ks = 0; ks < 2; ks++)
    qf[ks] = *(const f16x8*)(
        Q + (((size_t)b * 4096 + qt * 64 + rg * 16 + l15) << 6) + ks * 32 + hi * 8);
  f32x4 o[8];
#pragma unroll
  for (int i = 0; i < 8; i++) o[i] = (f32x4){0, 0, 0, 0};
  float mrow = -1e30f, lrow = 0.f;

  int cbase = hi * 16;

#define STAGE(kt)                                                                \
  {                                                                              \
    {                                                                            \
      int chunk = tid;                                                           \
      int row = chunk >> 3, cc = chunk & 7, scc = cc ^ (row & 7);                \
      gload16(Kb + (((kt) * 64 + row) << 6) + scc * 8,                           \
              (char*)Klds + chunk * 16);                                         \
    }                                                                            \
    _Pragma("unroll") for (int i = 0; i < 4; i++) {                              \
      int chunk = i * 512 + tid;                                                 \
      int row = chunk >> 3, cc = chunk & 7, scc = cc ^ (row & 7);                \
      gload16(Vb + ((size_t)row << 10) + (kt) * 64 + scc * 8,                    \
              (char*)Vlds + chunk * 16);                                         \
    }                                                                            \
  }

  STAGE(0);
  __syncthreads();
  for (int kt = 0; kt < 16; ++kt) {
    // ---- S^T = K Q^T: lane holds q-row l15, keys mf*16+hi*4+r
    f32x4 s[4];
#pragma unroll
    for (int mf = 0; mf < 4; mf++) s[mf] = (f32x4){0, 0, 0, 0};
#pragma unroll
    for (int ks = 0; ks < 2; ks++) {
      f16x8 kf[4];
#pragma unroll
      for (int mf = 0; mf < 4; mf++) {
        int row = mf * 16 + l15;
        kf[mf] = *(const f16x8*)((const char*)Klds + row * 128 +
                                 ((cbase + ks * 64) ^ ((row & 7) << 4)));
      }
#pragma unroll
      for (int mf = 0; mf < 4; mf++) s[mf] = MFMA16(kf[mf], qf[ks], s[mf]);
    }
    // ---- lane-local online softmax (defer-max THR=8)
    float t0 = fmaxf(fmaxf(s[0][0], s[1][0]), fmaxf(s[2][0], s[3][0]));
    float t1 = fmaxf(fmaxf(s[0][1], s[1][1]), fmaxf(s[2][1], s[3][1]));
    float t2 = fmaxf(fmaxf(s[0][2], s[1][2]), fmaxf(s[2][2], s[3][2]));
    float t3 = fmaxf(fmaxf(s[0][3], s[1][3]), fmaxf(s[2][3], s[3][3]));
    float mx = fmaxf(fmaxf(t0, t1), fmaxf(t2, t3));
    mx = fmaxf(mx, __shfl_xor(mx, 16, 64));
    mx = fmaxf(mx, __shfl_xor(mx, 32, 64));
    if (__any(mx > mrow + 8.f)) {
      float mnew = fmaxf(mrow, mx);
      float corr = __builtin_amdgcn_exp2f((mrow - mnew) * L2E);
      lrow *= corr;
      mrow = mnew;
#pragma unroll
      for (int r = 0; r < 4; r++) {
        float cr = __shfl(corr, (hi << 4) + (hi << 2) + r, 64);
#pragma unroll
        for (int cf = 0; cf < 8; cf++) o[cf][r] *= cr;
      }
    }
    // ---- exp -> pack -> sum, fused per mf (only 4 e-values live)
    {
      float lsumt = 0.f;
#pragma unroll
      for (int mf = 0; mf < 4; mf++) {
        float e0 = __builtin_amdgcn_exp2f((s[mf][0] - mrow) * L2E);
        float e1 = __builtin_amdgcn_exp2f((s[mf][1] - mrow) * L2E);
        float e2 = __builtin_amdgcn_exp2f((s[mf][2] - mrow) * L2E);
        float e3 = __builtin_amdgcn_exp2f((s[mf][3] - mrow) * L2E);
        f16x4 w = {(f16)e0, (f16)e1, (f16)e2, (f16)e3};
        *(f16x4*)((char*)Pw + l15 * 144 + mf * 32 + hi * 8) = w;
        lsumt += (e0 + e1) + (e2 + e3);
      }
      lsumt += __shfl_xor(lsumt, 16, 64);
      lsumt += __shfl_xor(lsumt, 32, 64);
      lrow += lsumt;
    }
    // ---- PV: this wave covers channels cg2*128 .. cg2*128+127
#pragma unroll
    for (int ks = 0; ks < 2; ks++) {
      f16x8 af = *(const f16x8*)((char*)Pw + l15 * 144 + ks * 64 + hi * 16);
      __builtin_amdgcn_s_setprio(1);
#pragma unroll
      for (int cg = 0; cg < 2; cg++) {
        f16x8 vf[4];
#pragma unroll
        for (int u = 0; u < 4; u++) {
          int row = (cg2 * 8 + cg * 4 + u) * 16 + l15;
          vf[u] = *(const f16x8*)((const char*)Vlds + row * 128 +
                                  ((cbase + ks * 64) ^ ((row & 7) << 4)));
        }
#pragma unroll
        for (int u = 0; u < 4; u++) o[cg * 4 + u] = MFMA16(af, vf[u], o[cg * 4 + u]);
      }
      __builtin_amdgcn_s_setprio(0);
    }
    if (kt < 15) {
      __syncthreads();   // all waves done reading Klds/Vlds (and Plds)
      STAGE(kt + 1);
      __syncthreads();   // staged data visible (vmcnt drain)
    }
  }
#undef STAGE

  // ================= fused output GEMM epilogue =================
  __syncthreads();  // everyone done with K/V/P reads; smem repurposed
  f16* attT = (f16*)smem;            // [64n][256c] swizzled, 32KB
  f16* xTT = (f16*)(smem + 32768);   // [64n][256k] swizzled, 32KB
#pragma unroll
  for (int i = 0; i < 4; i++) {
    int chunk = i * 512 + tid;
    int row = chunk >> 5, cc = chunk & 31, scc = cc ^ (row & 7);
    gload16(xT + (((size_t)b * 4096 + qt * 64 + row) << 8) + scc * 8,
            (char*)xTT + chunk * 16);
  }
  {
    float inv = 1.f / lrow;
    int nb = rg * 16 + hi * 4;
#pragma unroll
    for (int r = 0; r < 4; r++) {
      float iv = __shfl(inv, (hi << 4) + (hi << 2) + r, 64);
      int n = nb + r;
#pragma unroll
      for (int cf = 0; cf < 8; cf++) {
        int c = cg2 * 128 + cf * 16 + l15;
        *(f16*)((char*)attT + n * 512 + ((c * 2) ^ ((n & 7) << 4))) =
            (f16)(o[cf][r] * iv);
      }
    }
  }
  __syncthreads();  // attT written, xTT staged (vmcnt drained by barrier)
  {
    f32x4 acc2[4][4];
#pragma unroll
    for (int mf = 0; mf < 4; mf++)
#pragma unroll
      for (int nf = 0; nf < 4; nf++) acc2[mf][nf] = (f32x4){0, 0, 0, 0};
    for (int kc = 0; kc < 16; ++kc) {
      const char* tile = (kc < 8) ? (const char*)attT : (const char*)xTT;
      int ub = (kc & 7) * 64 + hi * 16;
      f16x8 af[4];
#pragma unroll
      for (int mf = 0; mf < 4; mf++)
        af[mf] = *(const f16x8*)(WcatP +
                                 ((size_t)(((wave * 4 + mf) * 16 + kc) * 64 + lane) << 3));
#pragma unroll
      for (int nf = 0; nf < 4; nf++) {
        int row = nf * 16 + l15;
        f16x8 bf = *(const f16x8*)(tile + row * 512 + (ub ^ ((row & 7) << 4)));
#pragma unroll
        for (int mf = 0; mf < 4; mf++)
          acc2[mf][nf] = MFMA16(af[mf], bf, acc2[mf][nf]);
      }
    }
#pragma unroll
    for (int mf = 0; mf < 4; mf++)
#pragma unroll
      for (int nf = 0; nf < 4; nf++)
#pragma unroll
        for (int r = 0; r < 4; r++) {
          int oo = wave * 64 + mf * 16 + hi * 4 + r;
          int n = qt * 64 + nf * 16 + l15;
          out[(((size_t)b * 512 + oo) << 12) + n] = acc2[mf][nf][r];
        }
  }
}

// -------------------------------------------------------------------------
extern "C" void kernel_launch(void* const* d_in, const int* in_sizes, int n_in,
                              void* d_out, int out_size, void* d_ws, size_t ws_size,
                              hipStream_t stream) {
  const float* x = (const float*)d_in[0];
  const float* wt = (const float*)d_in[1];
  const float* wp = (const float*)d_in[2];
  const float* wg = (const float*)d_in[3];
  const float* wo = (const float*)d_in[4];
  const float* wr = (const float*)d_in[5];
  const float* gm = (const float*)d_in[6];
  float* out = (float*)d_out;
  char* ws = (char*)d_ws;
  const size_t MB = 1024 * 1024;
  f16* xT = (f16*)(ws);
  f16* Qb = (f16*)(ws + 16 * MB);
  f16* Kp = (f16*)(ws + 20 * MB);
  f16* Vb = (f16*)(ws + 21 * MB);
  f16* Wproj = (f16*)(ws + 25 * MB);
  f16* WcatP = (f16*)(ws + 25 * MB + 512 * 1024);

  hipLaunchKernelGGL(k_prep_w, dim3(1408), dim3(256), 0, stream, wt, wp, wg, wo, wr, gm,
                     Wproj, WcatP);
  hipLaunchKernelGGL(k_transpose, dim3(4, 64, 8), dim3(256), 0, stream, x, xT);
  hipLaunchKernelGGL(k_gemm_projq, dim3(32, 6, 8), dim3(256), 0, stream, xT, Wproj, Qb,
                     Kp, Vb);
  hipLaunchKernelGGL(k_flash, dim3(64, 8), dim3(512), 0, stream, Qb, Kp, Vb, xT, WcatP,
                     out);
}

// Round 21
// 96.234 us; speedup vs baseline: 2.4804x; 1.0159x over previous
//
#include <hip/hip_runtime.h>

// NonLocalBlock (SAGAN non-local) fused pipeline for MI355X / gfx950.
// B=8, Cin=256, H=W=64 (HW=4096), Cout=512. Workspace (~46 MB of d_ws):
//   [0,16MB)   xT    fp16 [8][4096][256]
//   [16,20MB)  Q     fp16 [8][4096][64]
//   [20,21MB)  Kp    fp16 [8][1024][64]
//   [21,25MB)  V     fp16 [8][256][1024]
//   [25MB+0)   Wproj fp16 [384][256]
//   [25MB+512K) WcatP fp16 [512][512] fragment-permuted
//
// R20->R21: decisive spill-vs-occupancy test, one variable: k_flash
// __launch_bounds__ (512,4) -> (512,2). Raises the per-wave reg cap to
// 256 -> zero spill (the kernel wants ~140 regs; at 128 it spilled ~11MB
// per dispatch through scratch inside the hot loop). Cost: ~2 waves/SIMD.
// Cross-round evidence: occupancy 20->34% bought only ~4us (R13->R14),
// spill has cost ~10us whenever present (R8/R17). Everything else R20.

typedef _Float16 f16;
typedef f16 f16x2 __attribute__((ext_vector_type(2)));
typedef f16 f16x4 __attribute__((ext_vector_type(4)));
typedef f16 f16x8 __attribute__((ext_vector_type(8)));
typedef float f32x4 __attribute__((ext_vector_type(4)));

#define MFMA16(a, b, c) __builtin_amdgcn_mfma_f32_16x16x32_f16((a), (b), (c), 0, 0, 0)

__device__ __forceinline__ void gload16(const void* src, void* dst_lds) {
  __builtin_amdgcn_global_load_lds(
      (const __attribute__((address_space(1))) void*)src,
      (__attribute__((address_space(3))) void*)dst_lds, 16, 0, 0);
}

// -------------------------------------------------------------------------
// Weight prep. Wproj as before. WcatP fragment-permuted:
//   Wcat[r][c] -> WcatP[(((r>>4)*16 + (c>>5))*64 + ((c>>3)&3)*16 + (r&15))*8 + (c&7)]
__global__ __launch_bounds__(256, 4)
void k_prep_w(const float* __restrict__ wt, const float* __restrict__ wp,
              const float* __restrict__ wg, const float* __restrict__ wo,
              const float* __restrict__ wr, const float* __restrict__ gamma,
              f16* __restrict__ Wproj, f16* __restrict__ WcatP) {
  int i = blockIdx.x * 256 + threadIdx.x;
  const float s = 0.08838834764831845f;    // sqrt(2/256)
  const float is2 = 0.7071067811865476f;   // 1/sqrt(2)
  if (i < 384 * 256) {
    float v = (i < 64 * 256) ? wt[i]
              : (i < 128 * 256 ? wp[i - 64 * 256] : wg[i - 128 * 256]);
    Wproj[i] = (f16)(v * s);
  } else {
    int j = i - 384 * 256;
    if (j < 512 * 512) {
      int r = j >> 9, c = j & 511;
      float v = (c < 256) ? wo[r * 256 + c] * (gamma[0] * s * is2)
                          : wr[r * 256 + (c - 256)] * (s * is2);
      int og = r >> 4, lr = r & 15, kc = c >> 5, h2 = (c >> 3) & 3, e = c & 7;
      WcatP[(((og * 16 + kc) * 64 + h2 * 16 + lr) << 3) + e] = (f16)v;
    }
  }
}

// -------------------------------------------------------------------------
// Transpose x [b][256][4096] fp32 -> xT [b][4096][256] fp16 via 64x64 LDS tiles.
__global__ __launch_bounds__(256, 4)
void k_transpose(const float* __restrict__ x, f16* __restrict__ xT) {
  __shared__ f16 tile[64 * 72];
  int b = blockIdx.z, nt = blockIdx.y, ct = blockIdx.x;
  int t = threadIdx.x;
  {
    int c = t >> 2, nch = (t & 3) * 16;
    const float* src = x + (((size_t)b * 256 + ct * 64 + c) << 12) + nt * 64 + nch;
    float4 v0 = *(const float4*)(src);
    float4 v1 = *(const float4*)(src + 4);
    float4 v2 = *(const float4*)(src + 8);
    float4 v3 = *(const float4*)(src + 12);
    f16x8 a = {(f16)v0.x, (f16)v0.y, (f16)v0.z, (f16)v0.w,
               (f16)v1.x, (f16)v1.y, (f16)v1.z, (f16)v1.w};
    f16x8 bb = {(f16)v2.x, (f16)v2.y, (f16)v2.z, (f16)v2.w,
                (f16)v3.x, (f16)v3.y, (f16)v3.z, (f16)v3.w};
    *(f16x8*)&tile[c * 72 + nch] = a;
    *(f16x8*)&tile[c * 72 + nch + 8] = bb;
  }
  __syncthreads();
  {
    int n = t >> 2, cch = (t & 3) * 16;
    f16 tmp[16];
#pragma unroll
    for (int i = 0; i < 16; i++) tmp[i] = tile[(cch + i) * 72 + n];
    f16x8 a, bb;
#pragma unroll
    for (int i = 0; i < 8; i++) { a[i] = tmp[i]; bb[i] = tmp[8 + i]; }
    f16* dst = xT + (((size_t)b * 4096 + nt * 64 + n) << 8) + ct * 64 + cch;
    *(f16x8*)dst = a;
    *(f16x8*)(dst + 8) = bb;
  }
}

// -------------------------------------------------------------------------
// Merged projection GEMM + fused 2x2 maxpool epilogue.
__global__ __launch_bounds__(256, 2)
void k_gemm_projq(const f16* __restrict__ xT, const f16* __restrict__ Wproj,
                  f16* __restrict__ Q, f16* __restrict__ Kp, f16* __restrict__ V) {
  __shared__ f16 lds[192 * 64];  // Alds [64*64] | Blds [128*64]; pool aliases
  f16* Alds = lds;
  f16* Blds = lds + 64 * 64;
  int b = blockIdx.z, mt = blockIdx.y, nt = blockIdx.x;
  int tid = threadIdx.x;
  int lane = tid & 63, wave = tid >> 6;
  int wm = wave >> 1, wn = wave & 1;
  int l15 = lane & 15, hi = lane >> 4;
  f32x4 acc[2][4];
#pragma unroll
  for (int mf = 0; mf < 2; mf++)
#pragma unroll
    for (int nf = 0; nf < 4; nf++) acc[mf][nf] = (f32x4){0, 0, 0, 0};
  const f16* Abase = Wproj + ((mt * 64) << 8);
  const f16* Bbase = xT + (((size_t)b * 4096 + nt * 128) << 8);
  for (int k0 = 0; k0 < 256; k0 += 64) {
    __syncthreads();
#pragma unroll
    for (int i = 0; i < 2; i++) {
      int chunk = i * 256 + tid;
      int row = chunk >> 3, cc = chunk & 7, scc = cc ^ (row & 7);
      gload16(Abase + (row << 8) + k0 + scc * 8, (char*)Alds + (i * 256 + wave * 64) * 16);
    }
#pragma unroll
    for (int i = 0; i < 4; i++) {
      int chunk = i * 256 + tid;
      int row = chunk >> 3, cc = chunk & 7, scc = cc ^ (row & 7);
      gload16(Bbase + (row << 8) + k0 + scc * 8, (char*)Blds + (i * 256 + wave * 64) * 16);
    }
    __syncthreads();
#pragma unroll
    for (int ks = 0; ks < 2; ks++) {
      int cb = (hi * 8 + ks * 32) * 2;
      f16x8 af[2], bf[4];
#pragma unroll
      for (int mf = 0; mf < 2; mf++) {
        int row = wm * 32 + mf * 16 + l15;
        af[mf] = *(const f16x8*)((const char*)Alds + row * 128 + (cb ^ ((row & 7) << 4)));
      }
#pragma unroll
      for (int nf = 0; nf < 4; nf++) {
        int row = wn * 64 + nf * 16 + l15;
        bf[nf] = *(const f16x8*)((const char*)Blds + row * 128 + (cb ^ ((row & 7) << 4)));
      }
#pragma unroll
      for (int mf = 0; mf < 2; mf++)
#pragma unroll
        for (int nf = 0; nf < 4; nf++) acc[mf][nf] = MFMA16(af[mf], bf[nf], acc[mf][nf]);
    }
  }
  if (mt == 0) {
#pragma unroll
    for (int mf = 0; mf < 2; mf++)
#pragma unroll
      for (int nf = 0; nf < 4; nf++)
#pragma unroll
        for (int r = 0; r < 4; r++) {
          int jl = wm * 32 + mf * 16 + hi * 4 + r;
          int n = nt * 128 + wn * 64 + nf * 16 + l15;
          Q[(((size_t)b * 4096 + n) << 6) + jl] = (f16)acc[mf][nf][r];
        }
  } else {
    __syncthreads();  // done reading Alds/Blds
    f16* Pool = lds;
#pragma unroll
    for (int mf = 0; mf < 2; mf++)
#pragma unroll
      for (int nf = 0; nf < 4; nf++)
#pragma unroll
        for (int r = 0; r < 4; r++) {
          int jl = wm * 32 + mf * 16 + hi * 4 + r;
          int col = wn * 64 + nf * 16 + l15;
          Pool[jl * 132 + col] = (f16)acc[mf][nf][r];
        }
    __syncthreads();
    if (mt == 1) {
      int m_l = tid >> 3;
      int jj8 = (tid & 7) * 8;
      f16x8 w;
#pragma unroll
      for (int i = 0; i < 8; i++) {
        int jj = jj8 + i;
        f16x2 p0 = *(const f16x2*)&Pool[jj * 132 + 2 * m_l];
        f16x2 p1 = *(const f16x2*)&Pool[jj * 132 + 64 + 2 * m_l];
        float v = fmaxf(fmaxf((float)p0[0], (float)p0[1]),
                        fmaxf((float)p1[0], (float)p1[1]));
        w[i] = (f16)v;
      }
      *(f16x8*)&Kp[((size_t)b * 1024 + nt * 32 + m_l) * 64 + jj8] = w;
    } else {
      int ch_l = tid >> 2;
      int m8 = (tid & 3) * 8;
      f16x8 w;
#pragma unroll
      for (int i = 0; i < 8; i++) {
        int mm = m8 + i;
        f16x2 p0 = *(const f16x2*)&Pool[ch_l * 132 + 2 * mm];
        f16x2 p1 = *(const f16x2*)&Pool[ch_l * 132 + 64 + 2 * mm];
        float v = fmaxf(fmaxf((float)p0[0], (float)p0[1]),
                        fmaxf((float)p1[0], (float)p1[1]));
        w[i] = (f16)v;
      }
      int ch = (mt - 2) * 64 + ch_l;
      *(f16x8*)&V[(((size_t)b * 256 + ch) << 10) + nt * 32 + m8] = w;
    }
  }
}

// -------------------------------------------------------------------------
// Flash attention + fused output GEMM. (512,2): 256-reg cap, zero spill.
__global__ __launch_bounds__(512, 2)
void k_flash(const f16* __restrict__ Q, const f16* __restrict__ Kp,
             const f16* __restrict__ V, const f16* __restrict__ xT,
             const f16* __restrict__ WcatP, float* __restrict__ out) {
  __shared__ char smem[65536];
  f16* Klds = (f16*)smem;              // 8KB  [key][ch] swizzled
  f16* Vlds = (f16*)(smem + 8192);     // 32KB [ch][key] swizzled
  f16* PldsB = (f16*)(smem + 40960);   // 9.2KB: 4 rg-slots x 16 x 72
  int b = blockIdx.y, qt = blockIdx.x;
  int tid = threadIdx.x;
  int lane = tid & 63, wave = tid >> 6;   // 8 waves
  int rg = wave >> 1, cg2 = wave & 1;     // row-group 0..3 (16q), ch-group 0..1
  int l15 = lane & 15, hi = lane >> 4;
  const f16* Kb = Kp + ((size_t)b << 16);
  const f16* Vb = V + ((size_t)b << 18);
  f16* Pw = PldsB + rg * 16 * 72;  // shared across the cg2 pair
  const float L2E = 1.44269504f;
  f16x8 qf[2];
#pragma unroll
  for (int ks = 0; ks < 2; ks++)
    qf[ks] = *(const f16x8*)(
        Q + (((size_t)b * 4096 + qt * 64 + rg * 16 + l15) << 6) + ks * 32 + hi * 8);
  f32x4 o[8];
#pragma unroll
  for (int i = 0; i < 8; i++) o[i] = (f32x4){0, 0, 0, 0};
  float mrow = -1e30f, lrow = 0.f;

  int cbase = hi * 16;

#define STAGE(kt)                                                                \
  {                                                                              \
    {                                                                            \
      int chunk = tid;                                                           \
      int row = chunk >> 3, cc = chunk & 7, scc = cc ^ (row & 7);                \
      gload16(Kb + (((kt) * 64 + row) << 6) + scc * 8,                           \
              (char*)Klds + chunk * 16);                                         \
    }                                                                            \
    _Pragma("unroll") for (int i = 0; i < 4; i++) {                              \
      int chunk = i * 512 + tid;                                                 \
      int row = chunk >> 3, cc = chunk & 7, scc = cc ^ (row & 7);                \
      gload16(Vb + ((size_t)row << 10) + (kt) * 64 + scc * 8,                    \
              (char*)Vlds + chunk * 16);                                         \
    }                                                                            \
  }

  STAGE(0);
  __syncthreads();
  for (int kt = 0; kt < 16; ++kt) {
    // ---- S^T = K Q^T: lane holds q-row l15, keys mf*16+hi*4+r
    f32x4 s[4];
#pragma unroll
    for (int mf = 0; mf < 4; mf++) s[mf] = (f32x4){0, 0, 0, 0};
#pragma unroll
    for (int ks = 0; ks < 2; ks++) {
      f16x8 kf[4];
#pragma unroll
      for (int mf = 0; mf < 4; mf++) {
        int row = mf * 16 + l15;
        kf[mf] = *(const f16x8*)((const char*)Klds + row * 128 +
                                 ((cbase + ks * 64) ^ ((row & 7) << 4)));
      }
#pragma unroll
      for (int mf = 0; mf < 4; mf++) s[mf] = MFMA16(kf[mf], qf[ks], s[mf]);
    }
    // ---- lane-local online softmax (defer-max THR=8)
    float t0 = fmaxf(fmaxf(s[0][0], s[1][0]), fmaxf(s[2][0], s[3][0]));
    float t1 = fmaxf(fmaxf(s[0][1], s[1][1]), fmaxf(s[2][1], s[3][1]));
    float t2 = fmaxf(fmaxf(s[0][2], s[1][2]), fmaxf(s[2][2], s[3][2]));
    float t3 = fmaxf(fmaxf(s[0][3], s[1][3]), fmaxf(s[2][3], s[3][3]));
    float mx = fmaxf(fmaxf(t0, t1), fmaxf(t2, t3));
    mx = fmaxf(mx, __shfl_xor(mx, 16, 64));
    mx = fmaxf(mx, __shfl_xor(mx, 32, 64));
    if (__any(mx > mrow + 8.f)) {
      float mnew = fmaxf(mrow, mx);
      float corr = __builtin_amdgcn_exp2f((mrow - mnew) * L2E);
      lrow *= corr;
      mrow = mnew;
#pragma unroll
      for (int r = 0; r < 4; r++) {
        float cr = __shfl(corr, (hi << 4) + (hi << 2) + r, 64);
#pragma unroll
        for (int cf = 0; cf < 8; cf++) o[cf][r] *= cr;
      }
    }
    // ---- exp -> pack -> sum, fused per mf (only 4 e-values live)
    {
      float lsumt = 0.f;
#pragma unroll
      for (int mf = 0; mf < 4; mf++) {
        float e0 = __builtin_amdgcn_exp2f((s[mf][0] - mrow) * L2E);
        float e1 = __builtin_amdgcn_exp2f((s[mf][1] - mrow) * L2E);
        float e2 = __builtin_amdgcn_exp2f((s[mf][2] - mrow) * L2E);
        float e3 = __builtin_amdgcn_exp2f((s[mf][3] - mrow) * L2E);
        f16x4 w = {(f16)e0, (f16)e1, (f16)e2, (f16)e3};
        *(f16x4*)((char*)Pw + l15 * 144 + mf * 32 + hi * 8) = w;
        lsumt += (e0 + e1) + (e2 + e3);
      }
      lsumt += __shfl_xor(lsumt, 16, 64);
      lsumt += __shfl_xor(lsumt, 32, 64);
      lrow += lsumt;
    }
    // ---- PV: this wave covers channels cg2*128 .. cg2*128+127
#pragma unroll
    for (int ks = 0; ks < 2; ks++) {
      f16x8 af = *(const f16x8*)((char*)Pw + l15 * 144 + ks * 64 + hi * 16);
      __builtin_amdgcn_s_setprio(1);
#pragma unroll
      for (int cg = 0; cg < 2; cg++) {
        f16x8 vf[4];
#pragma unroll
        for (int u = 0; u < 4; u++) {
          int row = (cg2 * 8 + cg * 4 + u) * 16 + l15;
          vf[u] = *(const f16x8*)((const char*)Vlds + row * 128 +
                                  ((cbase + ks * 64) ^ ((row & 7) << 4)));
        }
#pragma unroll
        for (int u = 0; u < 4; u++) o[cg * 4 + u] = MFMA16(af, vf[u], o[cg * 4 + u]);
      }
      __builtin_amdgcn_s_setprio(0);
    }
    if (kt < 15) {
      __syncthreads();   // all waves done reading Klds/Vlds (and Plds)
      STAGE(kt + 1);
      __syncthreads();   // staged data visible (vmcnt drain)
    }
  }
#undef STAGE

  // ================= fused output GEMM epilogue =================
  __syncthreads();  // everyone done with K/V/P reads; smem repurposed
  f16* attT = (f16*)smem;            // [64n][256c] swizzled, 32KB
  f16* xTT = (f16*)(smem + 32768);   // [64n][256k] swizzled, 32KB
#pragma unroll
  for (int i = 0; i < 4; i++) {
    int chunk = i * 512 + tid;
    int row = chunk >> 5, cc = chunk & 31, scc = cc ^ (row & 7);
    gload16(xT + (((size_t)b * 4096 + qt * 64 + row) << 8) + scc * 8,
            (char*)xTT + chunk * 16);
  }
  {
    float inv = 1.f / lrow;
    int nb = rg * 16 + hi * 4;
#pragma unroll
    for (int r = 0; r < 4; r++) {
      float iv = __shfl(inv, (hi << 4) + (hi << 2) + r, 64);
      int n = nb + r;
#pragma unroll
      for (int cf = 0; cf < 8; cf++) {
        int c = cg2 * 128 + cf * 16 + l15;
        *(f16*)((char*)attT + n * 512 + ((c * 2) ^ ((n & 7) << 4))) =
            (f16)(o[cf][r] * iv);
      }
    }
  }
  __syncthreads();  // attT written, xTT staged (vmcnt drained by barrier)
  {
    f32x4 acc2[4][4];
#pragma unroll
    for (int mf = 0; mf < 4; mf++)
#pragma unroll
      for (int nf = 0; nf < 4; nf++) acc2[mf][nf] = (f32x4){0, 0, 0, 0};
    for (int kc = 0; kc < 16; ++kc) {
      const char* tile = (kc < 8) ? (const char*)attT : (const char*)xTT;
      int ub = (kc & 7) * 64 + hi * 16;
      f16x8 af[4];
#pragma unroll
      for (int mf = 0; mf < 4; mf++)
        af[mf] = *(const f16x8*)(WcatP +
                                 ((size_t)(((wave * 4 + mf) * 16 + kc) * 64 + lane) << 3));
#pragma unroll
      for (int nf = 0; nf < 4; nf++) {
        int row = nf * 16 + l15;
        f16x8 bf = *(const f16x8*)(tile + row * 512 + (ub ^ ((row & 7) << 4)));
#pragma unroll
        for (int mf = 0; mf < 4; mf++)
          acc2[mf][nf] = MFMA16(af[mf], bf, acc2[mf][nf]);
      }
    }
#pragma unroll
    for (int mf = 0; mf < 4; mf++)
#pragma unroll
      for (int nf = 0; nf < 4; nf++)
#pragma unroll
        for (int r = 0; r < 4; r++) {
          int oo = wave * 64 + mf * 16 + hi * 4 + r;
          int n = qt * 64 + nf * 16 + l15;
          out[(((size_t)b * 512 + oo) << 12) + n] = acc2[mf][nf][r];
        }
  }
}

// -------------------------------------------------------------------------
extern "C" void kernel_launch(void* const* d_in, const int* in_sizes, int n_in,
                              void* d_out, int out_size, void* d_ws, size_t ws_size,
                              hipStream_t stream) {
  const float* x = (const float*)d_in[0];
  const float* wt = (const float*)d_in[1];
  const float* wp = (const float*)d_in[2];
  const float* wg = (const float*)d_in[3];
  const float* wo = (const float*)d_in[4];
  const float* wr = (const float*)d_in[5];
  const float* gm = (const float*)d_in[6];
  float* out = (float*)d_out;
  char* ws = (char*)d_ws;
  const size_t MB = 1024 * 1024;
  f16* xT = (f16*)(ws);
  f16* Qb = (f16*)(ws + 16 * MB);
  f16* Kp = (f16*)(ws + 20 * MB);
  f16* Vb = (f16*)(ws + 21 * MB);
  f16* Wproj = (f16*)(ws + 25 * MB);
  f16* WcatP = (f16*)(ws + 25 * MB + 512 * 1024);

  hipLaunchKernelGGL(k_prep_w, dim3(1408), dim3(256), 0, stream, wt, wp, wg, wo, wr, gm,
                     Wproj, WcatP);
  hipLaunchKernelGGL(k_transpose, dim3(4, 64, 8), dim3(256), 0, stream, x, xT);
  hipLaunchKernelGGL(k_gemm_projq, dim3(32, 6, 8), dim3(256), 0, stream, xT, Wproj, Qb,
                     Kp, Vb);
  hipLaunchKernelGGL(k_flash, dim3(64, 8), dim3(512), 0, stream, Qb, Kp, Vb, xT, WcatP,
                     out);
}